// Round 6
// baseline (503.680 us; speedup 1.0000x reference)
//
#include <hip/hip_runtime.h>

// Swin-style double-window attention, MI355X. bf16-MFMA GEMMs + MFMA attention.
// B=32, C=256, H=W=64, WS=8, SHIFT=4, HEADS=8, DK=32, L=64, NW=64.
//
// Global intermediate layouts (per batch):
//   Qp, Kp : [px 4096][ch 256] bf16  (plain conv output, Q pre-scaled)
//   Vc     : [ch 256][px 4096] bf16
//   Yb     : [ch 256][px 4096] bf16  (attention output, shifted-map coords)
// The -SHIFT channel-half roll == heads 4..7 read shifted pixels; handled as
// a gather inside attn (load) and proj (+SHIFT gather, ch>=128).

typedef __attribute__((ext_vector_type(8))) short bf16x8;
typedef __attribute__((ext_vector_type(4))) float f32x4;

__device__ __forceinline__ ushort f2bf(float f) {
  uint u = __float_as_uint(f);
  return (ushort)((u + 0x7fffu + ((u >> 16) & 1u)) >> 16);
}

// LDS swizzle for 64-B rows (4 x 16B slots): XOR slot with row bits -> <=2-way
#define SWZ2(r) ((((r) & 3) ^ (((r) >> 2) & 3)) << 4)

// ------------------------------------------------------------- converters
__global__ __launch_bounds__(256) void w2b_kernel(const float* __restrict__ wq,
                                                  const float* __restrict__ wkv,
                                                  const float* __restrict__ wproj,
                                                  ushort* __restrict__ Wb) {
  const int i = (blockIdx.x * 256 + threadIdx.x) * 4;
  const int row = i >> 8;
  const float* src = (row < 256) ? (wq + i)
                   : (row < 768) ? (wkv + (i - 65536))
                                 : (wproj + (i - 196608));
  const float4 f = *reinterpret_cast<const float4*>(src);
  ushort4 u;
  u.x = f2bf(f.x); u.y = f2bf(f.y); u.z = f2bf(f.z); u.w = f2bf(f.w);
  *reinterpret_cast<ushort4*>(Wb + i) = u;
}

// ------------------------------------------------------------- kernel A
// D[oc][px] = sum_c W[oc][c] * x[c][px]. Tile 128oc x 128px, K=256, BK=32,
// double-buffered (32 KB LDS). fp32 x loaded directly, converted in-reg.
__global__ __launch_bounds__(256) void qkv_mfma_kernel(
    const float* __restrict__ x, const ushort* __restrict__ Wb,
    const float* __restrict__ bq, const float* __restrict__ bkv,
    ushort* __restrict__ Qp, ushort* __restrict__ Kp, ushort* __restrict__ Vc,
    int b0) {
  const int ot = blockIdx.x;       // 0..5 -> out-ch [ot*128, ot*128+128)
  const int pt = blockIdx.y & 31;  // pixel tile (128 px)
  const int lb = blockIdx.y >> 5;  // chunk-local batch
  const int pix0 = pt * 128;

  __shared__ __align__(16) ushort lds[2][2][4096];  // [buf][0=W,1=X][128r*32c]

  const int tid = threadIdx.x;
  const int l = tid & 63, wv = tid >> 6;
  const int wr = wv >> 1, wc = wv & 1;  // 2x2 wave grid, 64x64 each
  const int l15 = l & 15, l4 = l >> 4;
  const int w_oc = tid >> 1, w_part = tid & 1;  // W staging
  const int pg = tid & 31, cq = tid >> 5;       // X staging

  const ushort* Wsrc = Wb + (size_t)(ot * 128) * 256;
  const float* Xsrc = x + ((size_t)(b0 + lb) << 20) + pix0;

  float4 xr[4];
  bf16x8 wreg[2];
  f32x4 acc[4][4] = {};

#define LOAD_REGS(KK)                                                         \
  {                                                                           \
    const int c0 = (KK) * 32;                                                 \
    _Pragma("unroll") for (int i = 0; i < 4; i++)                             \
        xr[i] = *reinterpret_cast<const float4*>(                             \
            Xsrc + ((size_t)(c0 + cq * 4 + i) << 12) + pg * 4);               \
    _Pragma("unroll") for (int k = 0; k < 2; k++)                             \
        wreg[k] = *reinterpret_cast<const bf16x8*>(                           \
            Wsrc + (size_t)w_oc * 256 + c0 + w_part * 16 + k * 8);            \
  }

#define WRITE_LDS(BUF)                                                        \
  {                                                                           \
    ushort* Wt = &lds[(BUF)][0][0];                                           \
    ushort* Xt = &lds[(BUF)][1][0];                                           \
    _Pragma("unroll") for (int k = 0; k < 2; k++)                             \
        *reinterpret_cast<bf16x8*>(                                           \
            (char*)Wt + w_oc * 64 +                                           \
            ((w_part * 32 + k * 16) ^ SWZ2(w_oc))) = wreg[k];                 \
    _Pragma("unroll") for (int j = 0; j < 4; j++) {                           \
      const int row = pg * 4 + j;                                             \
      ushort4 v;                                                              \
      v.x = f2bf(j == 0 ? xr[0].x : j == 1 ? xr[0].y : j == 2 ? xr[0].z       \
                                                              : xr[0].w);     \
      v.y = f2bf(j == 0 ? xr[1].x : j == 1 ? xr[1].y : j == 2 ? xr[1].z       \
                                                              : xr[1].w);     \
      v.z = f2bf(j == 0 ? xr[2].x : j == 1 ? xr[2].y : j == 2 ? xr[2].z       \
                                                              : xr[2].w);     \
      v.w = f2bf(j == 0 ? xr[3].x : j == 1 ? xr[3].y : j == 2 ? xr[3].z       \
                                                              : xr[3].w);     \
      *reinterpret_cast<ushort4*>((char*)Xt + row * 64 +                      \
                                  ((cq * 8) ^ SWZ2(row))) = v;                \
    }                                                                         \
  }

  LOAD_REGS(0)
  WRITE_LDS(0)
  __syncthreads();

#pragma unroll
  for (int kk = 0; kk < 8; kk++) {
    if (kk < 7) LOAD_REGS(kk + 1)
    const ushort* Wt = &lds[kk & 1][0][0];
    const ushort* Xt = &lds[kk & 1][1][0];
    bf16x8 a[4], bfr[4];
#pragma unroll
    for (int m = 0; m < 4; m++) {
      const int row = wr * 64 + m * 16 + l15;
      a[m] = *reinterpret_cast<const bf16x8*>(
          (const char*)Wt + row * 64 + ((l4 * 16) ^ SWZ2(row)));
    }
#pragma unroll
    for (int n = 0; n < 4; n++) {
      const int row = wc * 64 + n * 16 + l15;
      bfr[n] = *reinterpret_cast<const bf16x8*>(
          (const char*)Xt + row * 64 + ((l4 * 16) ^ SWZ2(row)));
    }
#pragma unroll
    for (int m = 0; m < 4; m++)
#pragma unroll
      for (int n = 0; n < 4; n++)
        acc[m][n] = __builtin_amdgcn_mfma_f32_16x16x32_bf16(a[m], bfr[n],
                                                            acc[m][n], 0, 0, 0);
    if (kk < 7) {
      WRITE_LDS((kk + 1) & 1)
      __syncthreads();
    }
  }

  // epilogue: bias (+Q scale), PLAIN coalesced stores
  const int mode = ot >> 1;  // 0=Q 1=K 2=V (uniform per block)
  const float scale = (mode == 0) ? 0.17677669529663687f : 1.0f;
#pragma unroll
  for (int m = 0; m < 4; m++) {
    const int o0 = ot * 128 + wr * 64 + m * 16 + (l4 << 2);
    const int ch0 = o0 & 255;
    const float4 b4 = *reinterpret_cast<const float4*>(
        (mode == 0) ? (bq + o0) : (bkv + o0 - 256));
    if (mode < 2) {
      ushort* dst = (mode == 0) ? Qp : Kp;
#pragma unroll
      for (int n = 0; n < 4; n++) {
        const int px = pix0 + wc * 64 + n * 16 + l15;
        ushort4 st;
        st.x = f2bf((acc[m][n][0] + b4.x) * scale);
        st.y = f2bf((acc[m][n][1] + b4.y) * scale);
        st.z = f2bf((acc[m][n][2] + b4.z) * scale);
        st.w = f2bf((acc[m][n][3] + b4.w) * scale);
        *reinterpret_cast<ushort4*>(
            dst + (((size_t)lb << 12) + px) * 256 + ch0) = st;
      }
    } else {
#pragma unroll
      for (int n = 0; n < 4; n++) {
        const int px = pix0 + wc * 64 + n * 16 + l15;
        Vc[((size_t)(lb * 256 + ch0 + 0) << 12) + px] = f2bf(acc[m][n][0] + b4.x);
        Vc[((size_t)(lb * 256 + ch0 + 1) << 12) + px] = f2bf(acc[m][n][1] + b4.y);
        Vc[((size_t)(lb * 256 + ch0 + 2) << 12) + px] = f2bf(acc[m][n][2] + b4.z);
        Vc[((size_t)(lb * 256 + ch0 + 3) << 12) + px] = f2bf(acc[m][n][3] + b4.w);
      }
    }
  }
#undef LOAD_REGS
#undef WRITE_LDS
}

// ------------------------------------------------------------- kernel B
// Per (window,head) MFMA attention with shift/window gather at load.
__global__ __launch_bounds__(256) void attn_kernel(
    const ushort* __restrict__ Qp, const ushort* __restrict__ Kp,
    const ushort* __restrict__ Vc, const float* __restrict__ rpb,
    ushort* __restrict__ Y) {
  const int bwh = blockIdx.x;  // (lb*64 + wi)*8 + head
  const int head = bwh & 7;
  const int bw = bwh >> 3;
  const int wi = bw & 63;
  const int lb = bw >> 6;
  const int wh = wi >> 3, ww = wi & 7;

  __shared__ __align__(16) ushort Qs[2048];  // Qt [l][c] swz; reused: Ybuf
  __shared__ __align__(16) ushort Ks[2048];  // Kt [l][c] swz
  __shared__ __align__(16) ushort Vs[2048];  // V  [c][l] swz
  __shared__ __align__(16) ushort Ps[4096];  // P  [t][s] bf16 swz
  __shared__ float Rs[232];

  const int tid = threadIdx.x;
  const ushort* Qsrc = Qp + ((size_t)lb << 20);
  const ushort* Ksrc = Kp + ((size_t)lb << 20);
  const ushort* Vsrc = Vc + ((size_t)lb << 20);

  {  // ---- Q/K gather: thread -> (l = row of Qt, part = 8-ch chunk)
    const int lq = tid >> 2, part = tid & 3;
    const int i = lq >> 3, j = lq & 7;
    int hh, wcol;
    if (head < 4) { hh = wh * 8 + i; wcol = ww * 8 + j; }
    else { hh = (wh * 8 + i + 4) & 63; wcol = (ww * 8 + j + 4) & 63; }
    const size_t poff = ((size_t)(hh * 64 + wcol)) * 256 + head * 32 + part * 8;
    const uint4 qv = *reinterpret_cast<const uint4*>(Qsrc + poff);
    const uint4 kv = *reinterpret_cast<const uint4*>(Ksrc + poff);
    *reinterpret_cast<uint4*>((char*)Qs + lq * 64 + ((part * 16) ^ SWZ2(lq))) = qv;
    *reinterpret_cast<uint4*>((char*)Ks + lq * 64 + ((part * 16) ^ SWZ2(lq))) = kv;
    // ---- V gather: thread -> (c, window row)
    const int cv = tid >> 3, iv = tid & 7;
    const ushort* vrow;
    uint4 vv;
    if (head < 4) {
      vrow = Vsrc + ((size_t)(head * 32 + cv) << 12) + (wh * 8 + iv) * 64;
      vv = *reinterpret_cast<const uint4*>(vrow + ww * 8);
    } else {
      vrow = Vsrc + ((size_t)(head * 32 + cv) << 12) + (((wh * 8 + iv + 4) & 63) * 64);
      const uint2 lo = *reinterpret_cast<const uint2*>(vrow + (ww * 8 + 4));
      const uint2 hi = *reinterpret_cast<const uint2*>(vrow + ((ww * 8 + 8) & 63));
      vv = make_uint4(lo.x, lo.y, hi.x, hi.y);
    }
    *reinterpret_cast<uint4*>((char*)Vs + cv * 128 + ((iv * 16) ^ ((cv & 7) << 4))) = vv;
    if (tid < 225) Rs[tid] = rpb[tid * 8 + head];
  }
  __syncthreads();

  const int l = tid & 63, wv = tid >> 6;
  const int t0 = wv * 16;
  const int l15 = l & 15, l4 = l >> 4;

  // ---- QK^T: S[t][s]
  f32x4 accQ[4] = {};
  {
    const int tr = t0 + l15;
    const bf16x8 af = *reinterpret_cast<const bf16x8*>(
        (const char*)Qs + tr * 64 + ((l4 * 16) ^ SWZ2(tr)));
#pragma unroll
    for (int nt = 0; nt < 4; nt++) {
      const int s = nt * 16 + l15;
      const bf16x8 bfv = *reinterpret_cast<const bf16x8*>(
          (const char*)Ks + s * 64 + ((l4 * 16) ^ SWZ2(s)));
      accQ[nt] = __builtin_amdgcn_mfma_f32_16x16x32_bf16(af, bfv, accQ[nt], 0, 0, 0);
    }
  }

  // ---- rel-pos bias + shift mask
#pragma unroll
  for (int nt = 0; nt < 4; nt++) {
    const int s = nt * 16 + l15;
    const int si = s >> 3, sj = s & 7;
    const int hs = wh * 8 + si, wsx = ww * 8 + sj;
    const int cls = (hs < 56 ? 0 : (hs < 60 ? 1 : 2)) * 3 +
                    (wsx < 56 ? 0 : (wsx < 60 ? 1 : 2));
#pragma unroll
    for (int r = 0; r < 4; r++) {
      const int t = t0 + l4 * 4 + r;
      const int ri = t >> 3, rj = t & 7;
      const int hr = wh * 8 + ri, wrx = ww * 8 + rj;
      const int clr = (hr < 56 ? 0 : (hr < 60 ? 1 : 2)) * 3 +
                      (wrx < 56 ? 0 : (wrx < 60 ? 1 : 2));
      float add = Rs[(ri - si + 7) * 15 + (rj - sj + 7)];
      if (clr != cls) add -= 100.f;
      accQ[nt][r] += add;
    }
  }

  // ---- softmax per row t
#pragma unroll
  for (int r = 0; r < 4; r++) {
    float mx = fmaxf(fmaxf(accQ[0][r], accQ[1][r]), fmaxf(accQ[2][r], accQ[3][r]));
#pragma unroll
    for (int off = 1; off < 16; off <<= 1) mx = fmaxf(mx, __shfl_xor(mx, off));
    float e0 = __expf(accQ[0][r] - mx), e1 = __expf(accQ[1][r] - mx);
    float e2 = __expf(accQ[2][r] - mx), e3 = __expf(accQ[3][r] - mx);
    float sm = (e0 + e1) + (e2 + e3);
#pragma unroll
    for (int off = 1; off < 16; off <<= 1) sm += __shfl_xor(sm, off);
    const float rinv = 1.0f / sm;
    const int t = t0 + l4 * 4 + r;
    const int swz = (t & 7) << 4;
    *(ushort*)((char*)Ps + t * 128 + (((0 * 16 + l15) * 2) ^ swz)) = f2bf(e0 * rinv);
    *(ushort*)((char*)Ps + t * 128 + (((1 * 16 + l15) * 2) ^ swz)) = f2bf(e1 * rinv);
    *(ushort*)((char*)Ps + t * 128 + (((2 * 16 + l15) * 2) ^ swz)) = f2bf(e2 * rinv);
    *(ushort*)((char*)Ps + t * 128 + (((3 * 16 + l15) * 2) ^ swz)) = f2bf(e3 * rinv);
  }

  // ---- PV: D2[c][t] = sum_s V[c][s] P[t][s]
  f32x4 acc2[2] = {};
#pragma unroll
  for (int kk = 0; kk < 2; kk++) {
    const int colb = kk * 64 + l4 * 16;
    const int tr = t0 + l15;
    const bf16x8 b2 = *reinterpret_cast<const bf16x8*>(
        (const char*)Ps + tr * 128 + (colb ^ ((tr & 7) << 4)));
#pragma unroll
    for (int mt = 0; mt < 2; mt++) {
      const int c = mt * 16 + l15;
      const bf16x8 a2 = *reinterpret_cast<const bf16x8*>(
          (const char*)Vs + c * 128 + (colb ^ ((c & 7) << 4)));
      acc2[mt] = __builtin_amdgcn_mfma_f32_16x16x32_bf16(a2, b2, acc2[mt], 0, 0, 0);
    }
  }

  __syncthreads();  // all QK reads of Qs done -> reuse as Ybuf [c 32][t 64]

#pragma unroll
  for (int mt = 0; mt < 2; mt++)
#pragma unroll
    for (int r = 0; r < 4; r++) {
      const int c = mt * 16 + l4 * 4 + r;
      const int t = t0 + l15;
      *(ushort*)((char*)Qs + c * 128 + ((t * 2) ^ ((c & 7) << 4))) =
          f2bf(acc2[mt][r]);
    }
  __syncthreads();

  // spatial store (shifted-map coords): 16B per thread
  {
    const int c = tid >> 3, chunk = tid & 7;
    const uint4 v = *reinterpret_cast<const uint4*>(
        (const char*)Qs + c * 128 + ((chunk * 16) ^ ((c & 7) << 4)));
    const int ch = head * 32 + c;
    const int hh = wh * 8 + chunk;
    *reinterpret_cast<uint4*>(Y + (((size_t)lb * 256 + ch) << 12) + hh * 64 +
                              ww * 8) = v;
  }
}

// ------------------------------------------------------------- kernel C
// out[oc][px] = sum_c Wp[oc][c] * Ysh[c][px]. BK=32 double-buffered, 32KB LDS.
__global__ __launch_bounds__(256) void proj_mfma_kernel(
    const ushort* __restrict__ Yb, const ushort* __restrict__ Wb,
    const float* __restrict__ bproj, float* __restrict__ out, int b0) {
  const int ot = blockIdx.x;       // 0..1
  const int pt = blockIdx.y & 31;
  const int lb = blockIdx.y >> 5;
  const int pix0 = pt * 128;

  __shared__ __align__(16) ushort lds[2][2][4096];  // [buf][0=W,1=Y][128r*32c]

  const int tid = threadIdx.x;
  const int l = tid & 63, wv = tid >> 6;
  const int wr = wv >> 1, wc = wv & 1;
  const int l15 = l & 15, l4 = l >> 4;
  const int w_oc = tid >> 1, w_part = tid & 1;
  const int pg = tid & 31, cq = tid >> 5;

  const ushort* Wsrc = Wb + (size_t)(768 + ot * 128) * 256;
  const ushort* Ysrc = Yb + ((size_t)lb << 20);

  const int P0 = pix0 + pg * 4;
  const int h0 = P0 >> 6, w0 = P0 & 63;
  const int Psh = ((h0 + 60) & 63) * 64 + ((w0 + 60) & 63);

  ushort4 xr[4];
  bf16x8 wreg[2];
  f32x4 acc[4][4] = {};

#define LOAD_REGS_C(KK)                                                       \
  {                                                                           \
    const int c0 = (KK) * 32;                                                 \
    const int srcP = (c0 & 128) ? Psh : P0;                                   \
    _Pragma("unroll") for (int i = 0; i < 4; i++)                             \
        xr[i] = *reinterpret_cast<const ushort4*>(                            \
            Ysrc + ((size_t)(c0 + cq * 4 + i) << 12) + srcP);                 \
    _Pragma("unroll") for (int k = 0; k < 2; k++)                             \
        wreg[k] = *reinterpret_cast<const bf16x8*>(                           \
            Wsrc + (size_t)w_oc * 256 + c0 + w_part * 16 + k * 8);            \
  }

#define WRITE_LDS_C(BUF)                                                      \
  {                                                                           \
    ushort* Wt = &lds[(BUF)][0][0];                                           \
    ushort* Xt = &lds[(BUF)][1][0];                                           \
    _Pragma("unroll") for (int k = 0; k < 2; k++)                             \
        *reinterpret_cast<bf16x8*>(                                           \
            (char*)Wt + w_oc * 64 +                                           \
            ((w_part * 32 + k * 16) ^ SWZ2(w_oc))) = wreg[k];                 \
    _Pragma("unroll") for (int j = 0; j < 4; j++) {                           \
      const int row = pg * 4 + j;                                             \
      ushort4 v;                                                              \
      v.x = (j == 0) ? xr[0].x : (j == 1) ? xr[0].y : (j == 2) ? xr[0].z      \
                                                               : xr[0].w;     \
      v.y = (j == 0) ? xr[1].x : (j == 1) ? xr[1].y : (j == 2) ? xr[1].z      \
                                                               : xr[1].w;     \
      v.z = (j == 0) ? xr[2].x : (j == 1) ? xr[2].y : (j == 2) ? xr[2].z      \
                                                               : xr[2].w;     \
      v.w = (j == 0) ? xr[3].x : (j == 1) ? xr[3].y : (j == 2) ? xr[3].z      \
                                                               : xr[3].w;     \
      *reinterpret_cast<ushort4*>((char*)Xt + row * 64 +                      \
                                  ((cq * 8) ^ SWZ2(row))) = v;                \
    }                                                                         \
  }

  LOAD_REGS_C(0)
  WRITE_LDS_C(0)
  __syncthreads();

#pragma unroll
  for (int kk = 0; kk < 8; kk++) {
    if (kk < 7) LOAD_REGS_C(kk + 1)
    const ushort* Wt = &lds[kk & 1][0][0];
    const ushort* Xt = &lds[kk & 1][1][0];
    bf16x8 a[4], bfr[4];
#pragma unroll
    for (int m = 0; m < 4; m++) {
      const int row = wr * 64 + m * 16 + l15;
      a[m] = *reinterpret_cast<const bf16x8*>(
          (const char*)Wt + row * 64 + ((l4 * 16) ^ SWZ2(row)));
    }
#pragma unroll
    for (int n = 0; n < 4; n++) {
      const int row = wc * 64 + n * 16 + l15;
      bfr[n] = *reinterpret_cast<const bf16x8*>(
          (const char*)Xt + row * 64 + ((l4 * 16) ^ SWZ2(row)));
    }
#pragma unroll
    for (int m = 0; m < 4; m++)
#pragma unroll
      for (int n = 0; n < 4; n++)
        acc[m][n] = __builtin_amdgcn_mfma_f32_16x16x32_bf16(a[m], bfr[n],
                                                            acc[m][n], 0, 0, 0);
    if (kk < 7) {
      WRITE_LDS_C((kk + 1) & 1)
      __syncthreads();
    }
  }

  const int b = b0 + lb;
#pragma unroll
  for (int m = 0; m < 4; m++) {
    const int o0 = ot * 128 + wr * 64 + m * 16 + (l4 << 2);
    const float4 b4 = *reinterpret_cast<const float4*>(bproj + o0);
#pragma unroll
    for (int n = 0; n < 4; n++) {
      const int P = pix0 + wc * 64 + n * 16 + l15;
      out[(((size_t)b * 256 + o0 + 0) << 12) + P] = acc[m][n][0] + b4.x;
      out[(((size_t)b * 256 + o0 + 1) << 12) + P] = acc[m][n][1] + b4.y;
      out[(((size_t)b * 256 + o0 + 2) << 12) + P] = acc[m][n][2] + b4.z;
      out[(((size_t)b * 256 + o0 + 3) << 12) + P] = acc[m][n][3] + b4.w;
    }
  }
#undef LOAD_REGS_C
#undef WRITE_LDS_C
}

// ------------------------------------------------------------- launcher
extern "C" void kernel_launch(void* const* d_in, const int* in_sizes, int n_in,
                              void* d_out, int out_size, void* d_ws,
                              size_t ws_size, hipStream_t stream) {
  const float* x = (const float*)d_in[0];
  const float* wq = (const float*)d_in[1];
  const float* bq = (const float*)d_in[2];
  const float* wkv = (const float*)d_in[3];
  const float* bkv = (const float*)d_in[4];
  const float* wproj = (const float*)d_in[5];
  const float* bproj = (const float*)d_in[6];
  const float* rpb = (const float*)d_in[7];
  float* out = (float*)d_out;

  const size_t perB = 1048576ull;                  // 256*4096 elems per batch
  const size_t wbBytes = 1024ull * 256ull * 2ull;  // 512 KB bf16 weights
  const size_t perBatchBytes = 4ull * perB * 2ull; // Qp,Kp,Vc,Yb bf16 = 8 MB

  int chunk = (int)((ws_size > wbBytes ? ws_size - wbBytes : 0) / perBatchBytes);
  if (chunk > 32) chunk = 32;
  if (chunk < 1) chunk = 1;

  char* p = (char*)d_ws;
  ushort* Wb = (ushort*)p; p += wbBytes;
  ushort* Qp = (ushort*)p; p += (size_t)chunk * perB * 2;
  ushort* Kp = (ushort*)p; p += (size_t)chunk * perB * 2;
  ushort* Vc = (ushort*)p; p += (size_t)chunk * perB * 2;
  ushort* Yb = (ushort*)p;

  w2b_kernel<<<256, 256, 0, stream>>>(wq, wkv, wproj, Wb);

  for (int b0 = 0; b0 < 32; b0 += chunk) {
    const int cb = (32 - b0 < chunk) ? (32 - b0) : chunk;
    qkv_mfma_kernel<<<dim3(6, cb * 32), 256, 0, stream>>>(x, Wb, bq, bkv,
                                                          Qp, Kp, Vc, b0);
    attn_kernel<<<cb * 512, 256, 0, stream>>>(Qp, Kp, Vc, rpb, Yb);
    proj_mfma_kernel<<<dim3(2, cb * 32), 256, 0, stream>>>(Yb, Wb, bproj,
                                                           out, b0);
  }
}